// Round 16
// baseline (212.724 us; speedup 1.0000x reference)
//
#include <hip/hip_runtime.h>
#include <hip/hip_bf16.h>
#include <cstdint>
#include <cstddef>

typedef __attribute__((ext_vector_type(4))) float f32x4;
typedef __attribute__((ext_vector_type(8))) short bf16x8;
using u16 = unsigned short;

#define SCLOG2E 0.18033688011112043f  // 0.125 * log2(e), folded into qw/qr

__device__ __forceinline__ u16 f2b(float f) {
    union { float f; uint32_t u; } x; x.f = f;
    uint32_t r = x.u + 0x7fffu + ((x.u >> 16) & 1u);
    return (u16)(r >> 16);
}
__device__ __forceinline__ float b2f(u16 u) {
    union { uint32_t u; float f; } x; x.u = (uint32_t)u << 16; return x.f;
}
// packed RNE f32x2 -> bf16x2 (T12 recipe; no builtin on gfx950)
__device__ __forceinline__ uint32_t cvtpk(float lo, float hi) {
    uint32_t r;
    asm("v_cvt_pk_bf16_f32 %0, %1, %2" : "=v"(r) : "v"(lo), "v"(hi));
    return r;
}

#define GLDS16(g, s)                                                        \
    __builtin_amdgcn_global_load_lds(                                       \
        (const __attribute__((address_space(1))) uint32_t*)(g),             \
        (__attribute__((address_space(3))) uint32_t*)(s), 16, 0, 0)

// ---------------- prep: converts + cat in ONE kernel ----------------
// cat is stored B-MAJOR: cat2[b*1024 + j][d]
__global__ __launch_bounds__(256) void prep_kernel(
    const float* __restrict__ mems, const float* __restrict__ w,
    const float* __restrict__ r, const float* __restrict__ Wq,
    const float* __restrict__ Wkv, const float* __restrict__ Wr,
    const float* __restrict__ Wo, u16* __restrict__ cat_b,
    u16* __restrict__ r_b, u16* __restrict__ Wq_b, u16* __restrict__ Wkv_b,
    u16* __restrict__ Wr_b, u16* __restrict__ Wo_b) {
    int bid = blockIdx.x;
    if (bid < 8192) {
        int col4 = threadIdx.x;
        float4 v;
        int b, oj;
        if (bid < 4096) {
            v = reinterpret_cast<const float4*>(mems)[(size_t)bid * 256 + col4];
            b = bid & 7; oj = bid >> 3;
        } else {
            int rrow = bid - 4096;
            v = reinterpret_cast<const float4*>(w)[(size_t)rrow * 256 + col4];
            b = rrow & 7; oj = 512 + (rrow >> 3);
        }
        uint2 o;
        o.x = (uint32_t)f2b(v.x) | ((uint32_t)f2b(v.y) << 16);
        o.y = (uint32_t)f2b(v.z) | ((uint32_t)f2b(v.w) << 16);
        reinterpret_cast<uint2*>(cat_b)[(size_t)(b * 1024 + oj) * 256 + col4] = o;
        return;
    }
    bid -= 8192;
    const float4* src;
    uint2* dst;
    if (bid < 1024)      { src = (const float4*)r;   dst = (uint2*)r_b; }
    else if (bid < 2048) { src = (const float4*)Wq;  dst = (uint2*)Wq_b;  bid -= 1024; }
    else if (bid < 4096) { src = (const float4*)Wkv; dst = (uint2*)Wkv_b; bid -= 2048; }
    else if (bid < 5120) { src = (const float4*)Wr;  dst = (uint2*)Wr_b;  bid -= 4096; }
    else                 { src = (const float4*)Wo;  dst = (uint2*)Wo_b;  bid -= 5120; }
    int idx = bid * 256 + threadIdx.x;
    float4 v = src[idx];
    uint2 o;
    o.x = (uint32_t)f2b(v.x) | ((uint32_t)f2b(v.y) << 16);
    o.y = (uint32_t)f2b(v.z) | ((uint32_t)f2b(v.w) << 16);
    dst[idx] = o;
}

// ---------------- kv-proj GEMM: 256x256 tile, 2-phase double-buffered (R9-proven) ----------------
__global__ __launch_bounds__(512, 1) void kv_gemm(const u16* __restrict__ catb,
                                                  const u16* __restrict__ Wkvb,
                                                  u16* __restrict__ kb,
                                                  u16* __restrict__ vtb) {
    __shared__ u16 sA[2][256][64];  // 64 KB
    __shared__ u16 sB[2][256][64];  // 64 KB
    const int tid = threadIdx.x;
    const int wid = tid >> 6, lane = tid & 63;
    const int lr = lane & 15, lg = lane >> 4;
    const int bm = blockIdx.x * 256, bn = blockIdx.y * 256;
    const int Wm = (wid >> 2) * 128, Wn = (wid & 3) * 64;
    const int srow = tid >> 3, scol = tid & 7;
    const int xs = lr & 7;
    const u16* A = catb + (size_t)bm * 1024;
    const u16* B = Wkvb + (size_t)bn * 1024;
    f32x4 acc[8][4] = {};

#pragma unroll
    for (int p = 0; p < 4; p++) {
        int row = p * 64 + srow;
        int cs = (scol ^ (row & 7)) * 8;
        GLDS16(A + (size_t)row * 1024 + cs, &sA[0][row][scol * 8]);
        GLDS16(B + (size_t)row * 1024 + cs, &sB[0][row][scol * 8]);
    }
    __syncthreads();

    int cur = 0;
    for (int t = 0; t < 16; t++) {
        if (t < 15) {
            const int k0n = (t + 1) * 64;
#pragma unroll
            for (int p = 0; p < 4; p++) {
                int row = p * 64 + srow;
                int cs = (scol ^ (row & 7)) * 8;
                GLDS16(A + (size_t)row * 1024 + k0n + cs, &sA[cur ^ 1][row][scol * 8]);
                GLDS16(B + (size_t)row * 1024 + k0n + cs, &sB[cur ^ 1][row][scol * 8]);
            }
        }
#pragma unroll
        for (int ks = 0; ks < 2; ks++) {
            bf16x8 af[8], bfr[4];
#pragma unroll
            for (int mi = 0; mi < 8; mi++)
                af[mi] = *reinterpret_cast<const bf16x8*>(
                    &sA[cur][Wm + mi * 16 + lr][((ks * 4 + lg) ^ xs) * 8]);
#pragma unroll
            for (int ni = 0; ni < 4; ni++)
                bfr[ni] = *reinterpret_cast<const bf16x8*>(
                    &sB[cur][Wn + ni * 16 + lr][((ks * 4 + lg) ^ xs) * 8]);
#pragma unroll
            for (int mi = 0; mi < 8; mi++)
#pragma unroll
                for (int ni = 0; ni < 4; ni++)
                    acc[mi][ni] = __builtin_amdgcn_mfma_f32_16x16x32_bf16(
                        af[mi], bfr[ni], acc[mi][ni], 0, 0, 0);
        }
        __syncthreads();
        cur ^= 1;
    }
#pragma unroll
    for (int mi = 0; mi < 8; mi++)
#pragma unroll
        for (int ni = 0; ni < 4; ni++) {
            const int m0 = bm + Wm + mi * 16 + lg * 4;
            const int c = bn + Wn + ni * 16 + lr;
            const int b = m0 >> 10, j0 = m0 & 1023;
            const int n = c >> 7, dd = c & 127;
            if (dd < 64) {
#pragma unroll
                for (int rr = 0; rr < 4; rr++)
                    kb[(((size_t)(b * 16 + n)) * 1024 + j0 + rr) * 64 + dd] =
                        f2b(acc[mi][ni][rr]);
            } else {
                uint2 pk;
                pk.x = (uint32_t)f2b(acc[mi][ni][0]) | ((uint32_t)f2b(acc[mi][ni][1]) << 16);
                pk.y = (uint32_t)f2b(acc[mi][ni][2]) | ((uint32_t)f2b(acc[mi][ni][3]) << 16);
                *reinterpret_cast<uint2*>(
                    vtb + (((size_t)(b * 16 + n)) * 64 + (dd - 64)) * 1024 + j0) = pk;
            }
        }
}

// ---------------- q + r projection GEMMs (128^2, single-barrier prefetch dbuf) ----------------
// qw/qr epilogue pre-scales by SCLOG2E so attn softmax is exp2(AC+BD) directly.
__global__ __launch_bounds__(256, 2) void qr_gemm(
    const u16* __restrict__ catb, const u16* __restrict__ Wqb,
    const u16* __restrict__ rb, const u16* __restrict__ Wrb,
    const float* __restrict__ bw, const float* __restrict__ brr,
    const float* __restrict__ br, u16* __restrict__ qwb,
    u16* __restrict__ qrb, u16* __restrict__ rkb) {
    __shared__ u16 sA[2][128][64];  // 32 KB
    __shared__ u16 sB[2][128][64];  // 32 KB
    const int idx = blockIdx.x;
    const u16 *A, *B;
    int bx, by, epi;
    if (idx < 256) {
        epi = 0; B = Wqb; bx = idx & 31; by = idx >> 5;
        int bm0 = bx * 128;  // m = b*512+i -> cat2 row b*1024 + 512 + i
        A = catb + ((size_t)(bm0 >> 9) * 1024 + 512 + (bm0 & 511)) * 1024;
    } else {
        epi = 2; B = Wrb;
        int l = idx - 256; bx = l & 7; by = l >> 3;
        A = rb + (size_t)bx * 128 * 1024;
    }
    const int tid = threadIdx.x;
    const int wid = tid >> 6, lane = tid & 63;
    const int lr = lane & 15, lg = lane >> 4;
    const int bm = bx * 128, bn = by * 128;
    const int wm = (wid >> 1) * 64, wn = (wid & 1) * 64;
    const int srow = tid >> 3, scol = tid & 7;
    f32x4 acc[4][4] = {};

#pragma unroll
    for (int p = 0; p < 4; p++) {
        int row = p * 32 + srow;
        GLDS16(A + (size_t)row * 1024 + scol * 8, &sA[0][row][scol * 8]);
        GLDS16(B + (size_t)(bn + row) * 1024 + scol * 8, &sB[0][row][scol * 8]);
    }
    __syncthreads();

    int cur = 0;
    for (int t = 0; t < 16; t++) {
        if (t < 15) {
            const int k0n = (t + 1) * 64;
#pragma unroll
            for (int p = 0; p < 4; p++) {
                int row = p * 32 + srow;
                GLDS16(A + (size_t)row * 1024 + k0n + scol * 8, &sA[cur ^ 1][row][scol * 8]);
                GLDS16(B + (size_t)(bn + row) * 1024 + k0n + scol * 8,
                       &sB[cur ^ 1][row][scol * 8]);
            }
        }
#pragma unroll
        for (int ks = 0; ks < 2; ks++) {
            bf16x8 af[4], bfr[4];
#pragma unroll
            for (int x = 0; x < 4; x++) {
                af[x] = *reinterpret_cast<const bf16x8*>(
                    &sA[cur][wm + x * 16 + lr][(ks * 4 + lg) * 8]);
                bfr[x] = *reinterpret_cast<const bf16x8*>(
                    &sB[cur][wn + x * 16 + lr][(ks * 4 + lg) * 8]);
            }
#pragma unroll
            for (int mi = 0; mi < 4; mi++)
#pragma unroll
                for (int ni = 0; ni < 4; ni++)
                    acc[mi][ni] = __builtin_amdgcn_mfma_f32_16x16x32_bf16(
                        af[mi], bfr[ni], acc[mi][ni], 0, 0, 0);
        }
        __syncthreads();
        cur ^= 1;
    }
#pragma unroll
    for (int mi = 0; mi < 4; mi++)
#pragma unroll
        for (int ni = 0; ni < 4; ni++) {
            const int m0 = bm + wm + mi * 16 + lg * 4;
            const int c = bn + wn + ni * 16 + lr;
            if (epi == 0) {
#pragma unroll
                for (int rr = 0; rr < 4; rr++) {
                    int m = m0 + rr;
                    qwb[(size_t)m * 1024 + c] = f2b((acc[mi][ni][rr] + bw[c]) * SCLOG2E);
                    qrb[(size_t)m * 1024 + c] = f2b((acc[mi][ni][rr] + brr[c]) * SCLOG2E);
                }
            } else {
                const int nh = c >> 6, d = c & 63;
#pragma unroll
                for (int rr = 0; rr < 4; rr++)
                    rkb[((size_t)nh * 1024 + m0 + rr) * 64 + d] = f2b(acc[mi][ni][rr] + br[c]);
            }
        }
}

// ---------------- out-proj GEMM (128^2, prefetch dbuf); y stored bf16 ----------------
__global__ __launch_bounds__(256, 2) void gemm_out(const u16* __restrict__ A,
                                                   const u16* __restrict__ B,
                                                   const float* __restrict__ wres,
                                                   const float* __restrict__ bo,
                                                   u16* __restrict__ y) {
    __shared__ u16 sA[2][128][64];
    __shared__ u16 sB[2][128][64];
    const int tid = threadIdx.x;
    const int wid = tid >> 6, lane = tid & 63;
    const int lr = lane & 15, lg = lane >> 4;
    const int bm = blockIdx.x * 128, bn = blockIdx.y * 128;
    const int wm = (wid >> 1) * 64, wn = (wid & 1) * 64;
    const int srow = tid >> 3, scol = tid & 7;
    f32x4 acc[4][4] = {};

#pragma unroll
    for (int p = 0; p < 4; p++) {
        int row = p * 32 + srow;
        GLDS16(A + (size_t)(bm + row) * 1024 + scol * 8, &sA[0][row][scol * 8]);
        GLDS16(B + (size_t)(bn + row) * 1024 + scol * 8, &sB[0][row][scol * 8]);
    }
    __syncthreads();

    int cur = 0;
    for (int t = 0; t < 16; t++) {
        if (t < 15) {
            const int k0n = (t + 1) * 64;
#pragma unroll
            for (int p = 0; p < 4; p++) {
                int row = p * 32 + srow;
                GLDS16(A + (size_t)(bm + row) * 1024 + k0n + scol * 8,
                       &sA[cur ^ 1][row][scol * 8]);
                GLDS16(B + (size_t)(bn + row) * 1024 + k0n + scol * 8,
                       &sB[cur ^ 1][row][scol * 8]);
            }
        }
#pragma unroll
        for (int ks = 0; ks < 2; ks++) {
            bf16x8 af[4], bfr[4];
#pragma unroll
            for (int x = 0; x < 4; x++) {
                af[x] = *reinterpret_cast<const bf16x8*>(
                    &sA[cur][wm + x * 16 + lr][(ks * 4 + lg) * 8]);
                bfr[x] = *reinterpret_cast<const bf16x8*>(
                    &sB[cur][wn + x * 16 + lr][(ks * 4 + lg) * 8]);
            }
#pragma unroll
            for (int mi = 0; mi < 4; mi++)
#pragma unroll
                for (int ni = 0; ni < 4; ni++)
                    acc[mi][ni] = __builtin_amdgcn_mfma_f32_16x16x32_bf16(
                        af[mi], bfr[ni], acc[mi][ni], 0, 0, 0);
        }
        __syncthreads();
        cur ^= 1;
    }
#pragma unroll
    for (int mi = 0; mi < 4; mi++)
#pragma unroll
        for (int ni = 0; ni < 4; ni++)
#pragma unroll
            for (int rr = 0; rr < 4; rr++) {
                int m = bm + wm + mi * 16 + lg * 4 + rr;
                int c = bn + wn + ni * 16 + lr;
                float v = wres[(size_t)m * 1024 + c] + fmaxf(acc[mi][ni][rr] + bo[c], 0.0f);
                y[(size_t)m * 1024 + c] = f2b(v);
            }
}

// ---------------- fused rel-attention: SWAPPED-operand MFMA + packed bf16 stores ----------------
// R15 staging/barriers/ring unchanged. QK^T and BD computed as mfma(K,Q)/mfma(rk,Q):
// each lane then holds 4 CONSECUTIVE score columns of ONE q-row (row=lr,
// cols c = fj*16+lg*4+rr), so BD-band and P stores pack via v_cvt_pk_bf16_f32 +
// ds_write_b64 (was 36 scalar f2b + 36 ds_write_b16 per tile/wave).
// Rel-shift: needed rk abs row = j+511-i; wave holds band positions p=fb*16+lg*4+rr
// (abs base j0+496-it); lane reads bdsT[lr][fj*16+lg*4+rr+15-lr]. Clamped rows
// (>1023) only feed masked (e=0) entries. PV and output layout unchanged.
__global__ __launch_bounds__(512, 2) void attn_kernel(const u16* __restrict__ qw,
                                                      const u16* __restrict__ qr,
                                                      const u16* __restrict__ kbuf,
                                                      const u16* __restrict__ vt,
                                                      const u16* __restrict__ rkb,
                                                      u16* __restrict__ attnv) {
    __shared__ uint4 ksh[64][8];                  // 8 KB
    __shared__ uint4 vsh[64][8];                  // 8 KB
    __shared__ uint4 rsh[192][8];                 // 24 KB, mod-3 chunk ring
    __shared__ __align__(16) u16 bdsT[8][16][84]; // 21 KB  [wave][qrow][band pos]
    __shared__ __align__(16) u16 ps[8][16][72];   // 18.4 KB [wave][qrow][col]
    const int bid = blockIdx.x;
    const int wg = (bid & 7) * 64 + (bid >> 3);
    const int i0 = ((wg & 3) ^ 3) * 128;
    const int bnid = wg >> 2;
    const int b = bnid & 7, n = bnid >> 3;
    const int tid = threadIdx.x, wid = tid >> 6, lane = tid & 63;
    const int lr = lane & 15, lg = lane >> 4;
    const int it = i0 + wid * 16;

    const u16* qwp = qw + ((size_t)(b * 512 + it + lr)) * 1024 + n * 64;
    const u16* qrp = qr + ((size_t)(b * 512 + it + lr)) * 1024 + n * 64;
    bf16x8 aqw[2], aqr[2];
#pragma unroll
    for (int ks = 0; ks < 2; ks++) {
        aqw[ks] = *reinterpret_cast<const bf16x8*>(qwp + (ks * 4 + lg) * 8);
        aqr[ks] = *reinterpret_cast<const bf16x8*>(qrp + (ks * 4 + lg) * 8);
    }
    const u16* kp = kbuf + ((size_t)(b * 16 + n)) * 65536;
    const u16* vp = vt + ((size_t)(b * 16 + n)) * 65536;
    const u16* rp = rkb + (size_t)n * 65536;

    f32x4 acc[4] = {};
    float lpart = 0.f;
    const int xs = lr & 7;
    const int rbase = 112 - 16 * wid;  // wave offset in the 192-row band
    const int jrb0 = 384 - i0;         // band base at t=0 (multiple of 64, >= 0)

    const int srow = tid >> 3, sc = tid & 7;

    // ---- prologue: stage K/V tile 0 + ALL 3 rk chunks of tile 0 via gload_lds ----
    {
        int cs = (sc ^ (srow & 7)) * 8;
        GLDS16(kp + (size_t)srow * 64 + cs, (char*)ksh + (size_t)(wid * 64) * 16);
        GLDS16(vp + (size_t)srow * 1024 + cs, (char*)vsh + (size_t)(wid * 64) * 16);
    }
#pragma unroll
    for (int p = 0; p < 3; p++) {
        int row = jrb0 + p * 64 + srow;  // <= 575, no clamp needed
        int cp = ((jrb0 >> 6) + p) % 3;
        GLDS16(rp + (size_t)row * 64 + ((sc ^ (row & 7)) * 8),
               (char*)rsh + (size_t)(cp * 512 + wid * 64) * 16);
    }
    __syncthreads();

    const int nt = (i0 + 703) >> 6;
    for (int t = 0; t < nt; t++) {
        const int j0 = t << 6;
        const int jrb = jrb0 + j0;
        const bool more = (t + 1 < nt);
        // ---- T14 issue-early: tile t+1 K/V/rk-chunk -> registers (3 x 16B) ----
        uint4 kreg, vreg, rreg;
        int rrow_u = 0;
        if (more) {
            const int j0n = j0 + 64;
            kreg = *reinterpret_cast<const uint4*>(
                kp + (size_t)(j0n + srow) * 64 + ((sc ^ (srow & 7)) * 8));
            vreg = *reinterpret_cast<const uint4*>(
                vp + (size_t)srow * 1024 + j0n + ((sc ^ (srow & 7)) * 8));
            rrow_u = jrb + 192 + srow;
            int grow = rrow_u > 1023 ? 1023 : rrow_u;
            rreg = *reinterpret_cast<const uint4*>(
                rp + (size_t)grow * 64 + ((sc ^ (rrow_u & 7)) * 8));
        }

        // ---- compute tile t (SWAPPED operands) ----
        __builtin_amdgcn_s_setprio(1);
        f32x4 s[4] = {};
#pragma unroll
        for (int fj = 0; fj < 4; fj++)
#pragma unroll
            for (int ks = 0; ks < 2; ks++) {
                bf16x8 ak = *reinterpret_cast<const bf16x8*>(
                    &ksh[fj * 16 + lr][(ks * 4 + lg) ^ xs]);
                s[fj] = __builtin_amdgcn_mfma_f32_16x16x32_bf16(ak, aqw[ks], s[fj], 0, 0, 0);
            }
        f32x4 bd[5] = {};
#pragma unroll
        for (int fb = 0; fb < 5; fb++) {
            int x = jrb + rbase + fb * 16;
            int slot = ((x >> 6) % 3) * 64 + (x & 63) + lr;
#pragma unroll
            for (int ks = 0; ks < 2; ks++) {
                bf16x8 brk = *reinterpret_cast<const bf16x8*>(
                    &rsh[slot][(ks * 4 + lg) ^ xs]);
                bd[fb] = __builtin_amdgcn_mfma_f32_16x16x32_bf16(brk, aqr[ks], bd[fb], 0, 0, 0);
            }
        }
        __builtin_amdgcn_s_setprio(0);
        // ---- packed BD-band store: 2 cvt_pk + 1 ds_write_b64 per fb ----
#pragma unroll
        for (int fb = 0; fb < 5; fb++) {
            uint2 pk2;
            pk2.x = cvtpk(bd[fb][0], bd[fb][1]);
            pk2.y = cvtpk(bd[fb][2], bd[fb][3]);
            *reinterpret_cast<uint2*>(&bdsT[wid][lr][fb * 16 + lg * 4]) = pk2;
        }

        // ---- softmax: lane-local q-row; packed P store ----
        const int lim = it + lr + 512 - j0;  // mask: c <= lim
#pragma unroll
        for (int fj = 0; fj < 4; fj++) {
            float e4[4];
#pragma unroll
            for (int rr = 0; rr < 4; rr++) {
                const int c = fj * 16 + lg * 4 + rr;
                float v = s[fj][rr] + b2f(bdsT[wid][lr][c + 15 - lr]);
                float e = (c <= lim) ? exp2f(v) : 0.0f;
                lpart += e;
                e4[rr] = e;
            }
            uint2 pk2;
            pk2.x = cvtpk(e4[0], e4[1]);
            pk2.y = cvtpk(e4[2], e4[3]);
            *reinterpret_cast<uint2*>(&ps[wid][lr][fj * 16 + lg * 4]) = pk2;
        }
        __builtin_amdgcn_s_setprio(1);
#pragma unroll
        for (int kc = 0; kc < 2; kc++) {
            bf16x8 ap = *reinterpret_cast<const bf16x8*>(&ps[wid][lr][kc * 32 + lg * 8]);
#pragma unroll
            for (int nd = 0; nd < 4; nd++) {
                bf16x8 bv = *reinterpret_cast<const bf16x8*>(
                    &vsh[nd * 16 + lr][(kc * 4 + lg) ^ xs]);
                acc[nd] = __builtin_amdgcn_mfma_f32_16x16x32_bf16(ap, bv, acc[nd], 0, 0, 0);
            }
        }
        __builtin_amdgcn_s_setprio(0);

        if (more) {
            __syncthreads();  // readers of tile t done; drains vmcnt -> regs valid
            ksh[srow][sc] = kreg;
            vsh[srow][sc] = vreg;
            {
                int cw = (jrb >> 6) % 3;  // chunk freed by this tile's reads
                rsh[cw * 64 + (rrow_u & 63)][sc] = rreg;
            }
            __syncthreads();  // writes visible before tile t+1 compute
        }
    }
    // row-sum l: reduce over the 4 lanes sharing lr, then redistribute to PV layout
    float xsum = lpart;
    xsum += __shfl_xor(xsum, 16);
    xsum += __shfl_xor(xsum, 32);
    float l[4];
#pragma unroll
    for (int rr = 0; rr < 4; rr++) l[rr] = __shfl(xsum, lg * 4 + rr);
#pragma unroll
    for (int nd = 0; nd < 4; nd++)
#pragma unroll
        for (int rr = 0; rr < 4; rr++) {
            int i = it + lg * 4 + rr;
            int d = nd * 16 + lr;
            attnv[((size_t)i * 8 + b) * 1024 + n * 64 + d] = f2b(acc[nd][rr] / l[rr]);
        }
}

// ---------------- LayerNorm over last dim (1024); y input bf16 ----------------
__global__ __launch_bounds__(256) void ln_kernel(const u16* __restrict__ y,
                                                 const float* __restrict__ gamma,
                                                 const float* __restrict__ beta,
                                                 float* __restrict__ out) {
    __shared__ float rs[8];
    int row = blockIdx.x, tid = threadIdx.x;
    ushort4 u = reinterpret_cast<const ushort4*>(y + (size_t)row * 1024)[tid];
    float v0 = b2f(u.x), v1 = b2f(u.y), v2 = b2f(u.z), v3 = b2f(u.w);
    float s = v0 + v1 + v2 + v3;
    float s2 = v0 * v0 + v1 * v1 + v2 * v2 + v3 * v3;
#pragma unroll
    for (int m = 1; m < 64; m <<= 1) {
        s += __shfl_xor(s, m);
        s2 += __shfl_xor(s2, m);
    }
    if ((tid & 63) == 0) {
        rs[tid >> 6] = s;
        rs[4 + (tid >> 6)] = s2;
    }
    __syncthreads();
    s = rs[0] + rs[1] + rs[2] + rs[3];
    s2 = rs[4] + rs[5] + rs[6] + rs[7];
    float mu = s * (1.0f / 1024.0f);
    float var = s2 * (1.0f / 1024.0f) - mu * mu;
    float inv = rsqrtf(var + 1e-5f);
    float4 g = reinterpret_cast<const float4*>(gamma)[tid];
    float4 be = reinterpret_cast<const float4*>(beta)[tid];
    float4 o;
    o.x = (v0 - mu) * inv * g.x + be.x;
    o.y = (v1 - mu) * inv * g.y + be.y;
    o.z = (v2 - mu) * inv * g.z + be.z;
    o.w = (v3 - mu) * inv * g.w + be.w;
    reinterpret_cast<float4*>(out + (size_t)row * 1024)[tid] = o;
}

extern "C" void kernel_launch(void* const* d_in, const int* in_sizes, int n_in,
                              void* d_out, int out_size, void* d_ws, size_t ws_size,
                              hipStream_t stream) {
    (void)in_sizes; (void)n_in; (void)out_size; (void)ws_size;
    const float* w_in  = (const float*)d_in[0];
    const float* r_in  = (const float*)d_in[1];
    const float* mems  = (const float*)d_in[2];
    const float* bw    = (const float*)d_in[3];
    const float* brr   = (const float*)d_in[4];
    const float* Wq    = (const float*)d_in[5];
    const float* Wkv   = (const float*)d_in[6];
    const float* Wr    = (const float*)d_in[7];
    const float* br    = (const float*)d_in[8];
    const float* Wo    = (const float*)d_in[9];
    const float* bo    = (const float*)d_in[10];
    const float* gamma = (const float*)d_in[11];
    const float* beta  = (const float*)d_in[12];

    char* base = (char*)d_ws;
    size_t off = 0;
    auto alloc = [&](size_t bytes) -> char* {
        char* p = base + off;
        off += (bytes + 255) & ~(size_t)255;
        return p;
    };
    u16* cat_b = (u16*)alloc((size_t)8192 * 1024 * 2);
    u16* r_b   = (u16*)alloc((size_t)1024 * 1024 * 2);
    u16* Wq_b  = (u16*)alloc((size_t)1024 * 1024 * 2);
    u16* Wkv_b = (u16*)alloc((size_t)2048 * 1024 * 2);
    u16* Wr_b  = (u16*)alloc((size_t)1024 * 1024 * 2);
    u16* Wo_b  = (u16*)alloc((size_t)1024 * 1024 * 2);
    u16* qw_b  = (u16*)alloc((size_t)4096 * 1024 * 2);
    u16* qr_b  = (u16*)alloc((size_t)4096 * 1024 * 2);
    u16* k_b   = (u16*)alloc((size_t)128 * 1024 * 64 * 2);
    u16* vt_b  = (u16*)alloc((size_t)128 * 64 * 1024 * 2);
    u16* rk_b  = (u16*)alloc((size_t)16 * 1024 * 64 * 2);
    u16* av_b  = (u16*)alloc((size_t)4096 * 1024 * 2);
    u16* y     = (u16*)cat_b;  // alias: cat dead after GEMMs; y (bf16) written after attention

    prep_kernel<<<14336, 256, 0, stream>>>(mems, w_in, r_in, Wq, Wkv, Wr, Wo,
                                           cat_b, r_b, Wq_b, Wkv_b, Wr_b, Wo_b);

    kv_gemm<<<dim3(32, 8), 512, 0, stream>>>(cat_b, Wkv_b, k_b, vt_b);
    qr_gemm<<<320, 256, 0, stream>>>(cat_b, Wq_b, r_b, Wr_b, bw, brr, br,
                                     qw_b, qr_b, rk_b);

    attn_kernel<<<512, 512, 0, stream>>>(qw_b, qr_b, k_b, vt_b, rk_b, av_b);

    gemm_out<<<dim3(32, 8), 256, 0, stream>>>(av_b, Wo_b, w_in, bo, y);

    ln_kernel<<<4096, 256, 0, stream>>>(y, gamma, beta, (float*)d_out);
}

// Round 17
// 184.051 us; speedup vs baseline: 1.1558x; 1.1558x over previous
//
#include <hip/hip_runtime.h>
#include <hip/hip_bf16.h>
#include <cstdint>
#include <cstddef>

typedef __attribute__((ext_vector_type(4))) float f32x4;
typedef __attribute__((ext_vector_type(8))) short bf16x8;
using u16 = unsigned short;

#define SCLOG2E 0.18033688011112043f  // 0.125 * log2(e), folded into qw/qr

__device__ __forceinline__ u16 f2b(float f) {
    union { float f; uint32_t u; } x; x.f = f;
    uint32_t r = x.u + 0x7fffu + ((x.u >> 16) & 1u);
    return (u16)(r >> 16);
}
__device__ __forceinline__ float b2f(u16 u) {
    union { uint32_t u; float f; } x; x.u = (uint32_t)u << 16; return x.f;
}

#define GLDS16(g, s)                                                        \
    __builtin_amdgcn_global_load_lds(                                       \
        (const __attribute__((address_space(1))) uint32_t*)(g),             \
        (__attribute__((address_space(3))) uint32_t*)(s), 16, 0, 0)

// ---------------- prep: converts + cat in ONE kernel ----------------
// cat is stored B-MAJOR: cat2[b*1024 + j][d]
__global__ __launch_bounds__(256) void prep_kernel(
    const float* __restrict__ mems, const float* __restrict__ w,
    const float* __restrict__ r, const float* __restrict__ Wq,
    const float* __restrict__ Wkv, const float* __restrict__ Wr,
    const float* __restrict__ Wo, u16* __restrict__ cat_b,
    u16* __restrict__ r_b, u16* __restrict__ Wq_b, u16* __restrict__ Wkv_b,
    u16* __restrict__ Wr_b, u16* __restrict__ Wo_b) {
    int bid = blockIdx.x;
    if (bid < 8192) {
        int col4 = threadIdx.x;
        float4 v;
        int b, oj;
        if (bid < 4096) {
            v = reinterpret_cast<const float4*>(mems)[(size_t)bid * 256 + col4];
            b = bid & 7; oj = bid >> 3;
        } else {
            int rrow = bid - 4096;
            v = reinterpret_cast<const float4*>(w)[(size_t)rrow * 256 + col4];
            b = rrow & 7; oj = 512 + (rrow >> 3);
        }
        uint2 o;
        o.x = (uint32_t)f2b(v.x) | ((uint32_t)f2b(v.y) << 16);
        o.y = (uint32_t)f2b(v.z) | ((uint32_t)f2b(v.w) << 16);
        reinterpret_cast<uint2*>(cat_b)[(size_t)(b * 1024 + oj) * 256 + col4] = o;
        return;
    }
    bid -= 8192;
    const float4* src;
    uint2* dst;
    if (bid < 1024)      { src = (const float4*)r;   dst = (uint2*)r_b; }
    else if (bid < 2048) { src = (const float4*)Wq;  dst = (uint2*)Wq_b;  bid -= 1024; }
    else if (bid < 4096) { src = (const float4*)Wkv; dst = (uint2*)Wkv_b; bid -= 2048; }
    else if (bid < 5120) { src = (const float4*)Wr;  dst = (uint2*)Wr_b;  bid -= 4096; }
    else                 { src = (const float4*)Wo;  dst = (uint2*)Wo_b;  bid -= 5120; }
    int idx = bid * 256 + threadIdx.x;
    float4 v = src[idx];
    uint2 o;
    o.x = (uint32_t)f2b(v.x) | ((uint32_t)f2b(v.y) << 16);
    o.y = (uint32_t)f2b(v.z) | ((uint32_t)f2b(v.w) << 16);
    dst[idx] = o;
}

// ---------------- kv-proj GEMM: 256x256 tile, 2-phase double-buffered (R9-proven) ----------------
__global__ __launch_bounds__(512, 1) void kv_gemm(const u16* __restrict__ catb,
                                                  const u16* __restrict__ Wkvb,
                                                  u16* __restrict__ kb,
                                                  u16* __restrict__ vtb) {
    __shared__ u16 sA[2][256][64];  // 64 KB
    __shared__ u16 sB[2][256][64];  // 64 KB
    const int tid = threadIdx.x;
    const int wid = tid >> 6, lane = tid & 63;
    const int lr = lane & 15, lg = lane >> 4;
    const int bm = blockIdx.x * 256, bn = blockIdx.y * 256;
    const int Wm = (wid >> 2) * 128, Wn = (wid & 3) * 64;
    const int srow = tid >> 3, scol = tid & 7;
    const int xs = lr & 7;
    const u16* A = catb + (size_t)bm * 1024;
    const u16* B = Wkvb + (size_t)bn * 1024;
    f32x4 acc[8][4] = {};

#pragma unroll
    for (int p = 0; p < 4; p++) {
        int row = p * 64 + srow;
        int cs = (scol ^ (row & 7)) * 8;
        GLDS16(A + (size_t)row * 1024 + cs, &sA[0][row][scol * 8]);
        GLDS16(B + (size_t)row * 1024 + cs, &sB[0][row][scol * 8]);
    }
    __syncthreads();

    int cur = 0;
    for (int t = 0; t < 16; t++) {
        if (t < 15) {
            const int k0n = (t + 1) * 64;
#pragma unroll
            for (int p = 0; p < 4; p++) {
                int row = p * 64 + srow;
                int cs = (scol ^ (row & 7)) * 8;
                GLDS16(A + (size_t)row * 1024 + k0n + cs, &sA[cur ^ 1][row][scol * 8]);
                GLDS16(B + (size_t)row * 1024 + k0n + cs, &sB[cur ^ 1][row][scol * 8]);
            }
        }
#pragma unroll
        for (int ks = 0; ks < 2; ks++) {
            bf16x8 af[8], bfr[4];
#pragma unroll
            for (int mi = 0; mi < 8; mi++)
                af[mi] = *reinterpret_cast<const bf16x8*>(
                    &sA[cur][Wm + mi * 16 + lr][((ks * 4 + lg) ^ xs) * 8]);
#pragma unroll
            for (int ni = 0; ni < 4; ni++)
                bfr[ni] = *reinterpret_cast<const bf16x8*>(
                    &sB[cur][Wn + ni * 16 + lr][((ks * 4 + lg) ^ xs) * 8]);
#pragma unroll
            for (int mi = 0; mi < 8; mi++)
#pragma unroll
                for (int ni = 0; ni < 4; ni++)
                    acc[mi][ni] = __builtin_amdgcn_mfma_f32_16x16x32_bf16(
                        af[mi], bfr[ni], acc[mi][ni], 0, 0, 0);
        }
        __syncthreads();
        cur ^= 1;
    }
#pragma unroll
    for (int mi = 0; mi < 8; mi++)
#pragma unroll
        for (int ni = 0; ni < 4; ni++) {
            const int m0 = bm + Wm + mi * 16 + lg * 4;
            const int c = bn + Wn + ni * 16 + lr;
            const int b = m0 >> 10, j0 = m0 & 1023;
            const int n = c >> 7, dd = c & 127;
            if (dd < 64) {
#pragma unroll
                for (int rr = 0; rr < 4; rr++)
                    kb[(((size_t)(b * 16 + n)) * 1024 + j0 + rr) * 64 + dd] =
                        f2b(acc[mi][ni][rr]);
            } else {
                uint2 pk;
                pk.x = (uint32_t)f2b(acc[mi][ni][0]) | ((uint32_t)f2b(acc[mi][ni][1]) << 16);
                pk.y = (uint32_t)f2b(acc[mi][ni][2]) | ((uint32_t)f2b(acc[mi][ni][3]) << 16);
                *reinterpret_cast<uint2*>(
                    vtb + (((size_t)(b * 16 + n)) * 64 + (dd - 64)) * 1024 + j0) = pk;
            }
        }
}

// ---------------- q + r projection GEMMs (128^2, single-barrier prefetch dbuf) ----------------
// qw/qr epilogue pre-scales by SCLOG2E so attn softmax is exp2(AC+BD) directly.
__global__ __launch_bounds__(256, 2) void qr_gemm(
    const u16* __restrict__ catb, const u16* __restrict__ Wqb,
    const u16* __restrict__ rb, const u16* __restrict__ Wrb,
    const float* __restrict__ bw, const float* __restrict__ brr,
    const float* __restrict__ br, u16* __restrict__ qwb,
    u16* __restrict__ qrb, u16* __restrict__ rkb) {
    __shared__ u16 sA[2][128][64];  // 32 KB
    __shared__ u16 sB[2][128][64];  // 32 KB
    const int idx = blockIdx.x;
    const u16 *A, *B;
    int bx, by, epi;
    if (idx < 256) {
        epi = 0; B = Wqb; bx = idx & 31; by = idx >> 5;
        int bm0 = bx * 128;  // m = b*512+i -> cat2 row b*1024 + 512 + i
        A = catb + ((size_t)(bm0 >> 9) * 1024 + 512 + (bm0 & 511)) * 1024;
    } else {
        epi = 2; B = Wrb;
        int l = idx - 256; bx = l & 7; by = l >> 3;
        A = rb + (size_t)bx * 128 * 1024;
    }
    const int tid = threadIdx.x;
    const int wid = tid >> 6, lane = tid & 63;
    const int lr = lane & 15, lg = lane >> 4;
    const int bm = bx * 128, bn = by * 128;
    const int wm = (wid >> 1) * 64, wn = (wid & 1) * 64;
    const int srow = tid >> 3, scol = tid & 7;
    f32x4 acc[4][4] = {};

#pragma unroll
    for (int p = 0; p < 4; p++) {
        int row = p * 32 + srow;
        GLDS16(A + (size_t)row * 1024 + scol * 8, &sA[0][row][scol * 8]);
        GLDS16(B + (size_t)(bn + row) * 1024 + scol * 8, &sB[0][row][scol * 8]);
    }
    __syncthreads();

    int cur = 0;
    for (int t = 0; t < 16; t++) {
        if (t < 15) {
            const int k0n = (t + 1) * 64;
#pragma unroll
            for (int p = 0; p < 4; p++) {
                int row = p * 32 + srow;
                GLDS16(A + (size_t)row * 1024 + k0n + scol * 8, &sA[cur ^ 1][row][scol * 8]);
                GLDS16(B + (size_t)(bn + row) * 1024 + k0n + scol * 8,
                       &sB[cur ^ 1][row][scol * 8]);
            }
        }
#pragma unroll
        for (int ks = 0; ks < 2; ks++) {
            bf16x8 af[4], bfr[4];
#pragma unroll
            for (int x = 0; x < 4; x++) {
                af[x] = *reinterpret_cast<const bf16x8*>(
                    &sA[cur][wm + x * 16 + lr][(ks * 4 + lg) * 8]);
                bfr[x] = *reinterpret_cast<const bf16x8*>(
                    &sB[cur][wn + x * 16 + lr][(ks * 4 + lg) * 8]);
            }
#pragma unroll
            for (int mi = 0; mi < 4; mi++)
#pragma unroll
                for (int ni = 0; ni < 4; ni++)
                    acc[mi][ni] = __builtin_amdgcn_mfma_f32_16x16x32_bf16(
                        af[mi], bfr[ni], acc[mi][ni], 0, 0, 0);
        }
        __syncthreads();
        cur ^= 1;
    }
#pragma unroll
    for (int mi = 0; mi < 4; mi++)
#pragma unroll
        for (int ni = 0; ni < 4; ni++) {
            const int m0 = bm + wm + mi * 16 + lg * 4;
            const int c = bn + wn + ni * 16 + lr;
            if (epi == 0) {
#pragma unroll
                for (int rr = 0; rr < 4; rr++) {
                    int m = m0 + rr;
                    qwb[(size_t)m * 1024 + c] = f2b((acc[mi][ni][rr] + bw[c]) * SCLOG2E);
                    qrb[(size_t)m * 1024 + c] = f2b((acc[mi][ni][rr] + brr[c]) * SCLOG2E);
                }
            } else {
                const int nh = c >> 6, d = c & 63;
#pragma unroll
                for (int rr = 0; rr < 4; rr++)
                    rkb[((size_t)nh * 1024 + m0 + rr) * 64 + d] = f2b(acc[mi][ni][rr] + br[c]);
            }
        }
}

// ---------------- out-proj GEMM (128^2, prefetch dbuf); y stored bf16 ----------------
__global__ __launch_bounds__(256, 2) void gemm_out(const u16* __restrict__ A,
                                                   const u16* __restrict__ B,
                                                   const float* __restrict__ wres,
                                                   const float* __restrict__ bo,
                                                   u16* __restrict__ y) {
    __shared__ u16 sA[2][128][64];
    __shared__ u16 sB[2][128][64];
    const int tid = threadIdx.x;
    const int wid = tid >> 6, lane = tid & 63;
    const int lr = lane & 15, lg = lane >> 4;
    const int bm = blockIdx.x * 128, bn = blockIdx.y * 128;
    const int wm = (wid >> 1) * 64, wn = (wid & 1) * 64;
    const int srow = tid >> 3, scol = tid & 7;
    f32x4 acc[4][4] = {};

#pragma unroll
    for (int p = 0; p < 4; p++) {
        int row = p * 32 + srow;
        GLDS16(A + (size_t)(bm + row) * 1024 + scol * 8, &sA[0][row][scol * 8]);
        GLDS16(B + (size_t)(bn + row) * 1024 + scol * 8, &sB[0][row][scol * 8]);
    }
    __syncthreads();

    int cur = 0;
    for (int t = 0; t < 16; t++) {
        if (t < 15) {
            const int k0n = (t + 1) * 64;
#pragma unroll
            for (int p = 0; p < 4; p++) {
                int row = p * 32 + srow;
                GLDS16(A + (size_t)(bm + row) * 1024 + k0n + scol * 8,
                       &sA[cur ^ 1][row][scol * 8]);
                GLDS16(B + (size_t)(bn + row) * 1024 + k0n + scol * 8,
                       &sB[cur ^ 1][row][scol * 8]);
            }
        }
#pragma unroll
        for (int ks = 0; ks < 2; ks++) {
            bf16x8 af[4], bfr[4];
#pragma unroll
            for (int x = 0; x < 4; x++) {
                af[x] = *reinterpret_cast<const bf16x8*>(
                    &sA[cur][wm + x * 16 + lr][(ks * 4 + lg) * 8]);
                bfr[x] = *reinterpret_cast<const bf16x8*>(
                    &sB[cur][wn + x * 16 + lr][(ks * 4 + lg) * 8]);
            }
#pragma unroll
            for (int mi = 0; mi < 4; mi++)
#pragma unroll
                for (int ni = 0; ni < 4; ni++)
                    acc[mi][ni] = __builtin_amdgcn_mfma_f32_16x16x32_bf16(
                        af[mi], bfr[ni], acc[mi][ni], 0, 0, 0);
        }
        __syncthreads();
        cur ^= 1;
    }
#pragma unroll
    for (int mi = 0; mi < 4; mi++)
#pragma unroll
        for (int ni = 0; ni < 4; ni++)
#pragma unroll
            for (int rr = 0; rr < 4; rr++) {
                int m = bm + wm + mi * 16 + lg * 4 + rr;
                int c = bn + wn + ni * 16 + lr;
                float v = wres[(size_t)m * 1024 + c] + fmaxf(acc[mi][ni][rr] + bo[c], 0.0f);
                y[(size_t)m * 1024 + c] = f2b(v);
            }
}

// ---------------- fused rel-attention: R15 body + nt LOAD-BALANCED block decode ----------------
// nt varies {10,12,14,16} with i0. 512 blocks = 2/CU; round-robin dispatch gives CU k
// blocks w2=k and w2=k+32 (period 32 per XCD). Old decode: pair(w2)==pair(w2+32) ->
// some CUs get 16+16=32 tiles (critical path) vs avg 26. New decode flips the pair
// index for w2>=32 so every CU sums to 26 tiles (16+10 or 14+12). Bijective:
// w2<32 covers bn 0..7 x all pairs; w2>=32 covers bn 8..15 x all pairs.
__global__ __launch_bounds__(512, 2) void attn_kernel(const u16* __restrict__ qw,
                                                      const u16* __restrict__ qr,
                                                      const u16* __restrict__ kbuf,
                                                      const u16* __restrict__ vt,
                                                      const u16* __restrict__ rkb,
                                                      u16* __restrict__ attnv) {
    __shared__ uint4 ksh[64][8];     // 8 KB
    __shared__ uint4 vsh[64][8];     // 8 KB
    __shared__ uint4 rsh[192][8];    // 24 KB, mod-3 chunk ring
    __shared__ u16 bds[8][16][82];   // 20.5 KB (bf16 BD band)
    __shared__ u16 ps[8][16][72];    // 18.4 KB
    const int bid = blockIdx.x;
    const int w2 = bid >> 3;
    int pr = w2 & 3;
    if (w2 >= 32) pr ^= 3;            // complement pair for the CU's second block
    const int i0 = (pr ^ 3) * 128;
    const int bnid = w2 >> 2;         // 0..15
    const int b = bnid & 7, n = ((bid & 7) << 1) | (bnid >> 3);
    const int tid = threadIdx.x, wid = tid >> 6, lane = tid & 63;
    const int lr = lane & 15, lg = lane >> 4;
    const int it = i0 + wid * 16;

    const u16* qwp = qw + ((size_t)(b * 512 + it + lr)) * 1024 + n * 64;
    const u16* qrp = qr + ((size_t)(b * 512 + it + lr)) * 1024 + n * 64;
    bf16x8 aqw[2], aqr[2];
#pragma unroll
    for (int ks = 0; ks < 2; ks++) {
        aqw[ks] = *reinterpret_cast<const bf16x8*>(qwp + (ks * 4 + lg) * 8);
        aqr[ks] = *reinterpret_cast<const bf16x8*>(qrp + (ks * 4 + lg) * 8);
    }
    const u16* kp = kbuf + ((size_t)(b * 16 + n)) * 65536;
    const u16* vp = vt + ((size_t)(b * 16 + n)) * 65536;
    const u16* rp = rkb + (size_t)n * 65536;

    f32x4 acc[4] = {};
    float lpart[4] = {0.f, 0.f, 0.f, 0.f};
    const int xs = lr & 7;
    const int rbase = 112 - 16 * wid;  // wave offset in the 192-row band
    const int jrb0 = 384 - i0;         // band base at t=0 (multiple of 64, >= 0)

    const int srow = tid >> 3, sc = tid & 7;

    // ---- prologue: stage K/V tile 0 + ALL 3 rk chunks of tile 0 via gload_lds ----
    {
        int cs = (sc ^ (srow & 7)) * 8;
        GLDS16(kp + (size_t)srow * 64 + cs, (char*)ksh + (size_t)(wid * 64) * 16);
        GLDS16(vp + (size_t)srow * 1024 + cs, (char*)vsh + (size_t)(wid * 64) * 16);
    }
#pragma unroll
    for (int p = 0; p < 3; p++) {
        int row = jrb0 + p * 64 + srow;  // <= 575, no clamp needed
        int cp = ((jrb0 >> 6) + p) % 3;
        GLDS16(rp + (size_t)row * 64 + ((sc ^ (row & 7)) * 8),
               (char*)rsh + (size_t)(cp * 512 + wid * 64) * 16);
    }
    __syncthreads();

    const int nt = (i0 + 703) >> 6;
    for (int t = 0; t < nt; t++) {
        const int j0 = t << 6;
        const int jrb = jrb0 + j0;
        const bool more = (t + 1 < nt);
        // ---- T14 issue-early: tile t+1 K/V/rk-chunk -> registers (3 x 16B) ----
        uint4 kreg, vreg, rreg;
        int rrow_u = 0;
        if (more) {
            const int j0n = j0 + 64;
            kreg = *reinterpret_cast<const uint4*>(
                kp + (size_t)(j0n + srow) * 64 + ((sc ^ (srow & 7)) * 8));
            vreg = *reinterpret_cast<const uint4*>(
                vp + (size_t)srow * 1024 + j0n + ((sc ^ (srow & 7)) * 8));
            rrow_u = jrb + 192 + srow;                    // new band rows of tile t+1
            int grow = rrow_u > 1023 ? 1023 : rrow_u;     // masked region only
            rreg = *reinterpret_cast<const uint4*>(
                rp + (size_t)grow * 64 + ((sc ^ (rrow_u & 7)) * 8));
        }

        // ---- compute tile t ----
        __builtin_amdgcn_s_setprio(1);
        f32x4 s[4] = {};
#pragma unroll
        for (int fj = 0; fj < 4; fj++)
#pragma unroll
            for (int ks = 0; ks < 2; ks++) {
                bf16x8 bk = *reinterpret_cast<const bf16x8*>(
                    &ksh[fj * 16 + lr][(ks * 4 + lg) ^ xs]);
                s[fj] = __builtin_amdgcn_mfma_f32_16x16x32_bf16(aqw[ks], bk, s[fj], 0, 0, 0);
            }
        f32x4 bd[5] = {};
#pragma unroll
        for (int fb = 0; fb < 5; fb++) {
            int x = jrb + rbase + fb * 16;  // abs row base (multiple of 16)
            int slot = ((x >> 6) % 3) * 64 + (x & 63) + lr;
#pragma unroll
            for (int ks = 0; ks < 2; ks++) {
                bf16x8 brk = *reinterpret_cast<const bf16x8*>(
                    &rsh[slot][(ks * 4 + lg) ^ xs]);
                bd[fb] = __builtin_amdgcn_mfma_f32_16x16x32_bf16(aqr[ks], brk, bd[fb], 0, 0, 0);
            }
        }
        __builtin_amdgcn_s_setprio(0);
#pragma unroll
        for (int fb = 0; fb < 5; fb++)
#pragma unroll
            for (int rr = 0; rr < 4; rr++)
                bds[wid][lg * 4 + rr][fb * 16 + lr] = f2b(bd[fb][rr]);

#pragma unroll
        for (int fj = 0; fj < 4; fj++)
#pragma unroll
            for (int rr = 0; rr < 4; rr++) {
                const int di = lg * 4 + rr;
                float v = s[fj][rr] + b2f(bds[wid][di][fj * 16 + lr + 15 - di]);
                float e = (j0 + fj * 16 + lr <= it + di + 512) ? exp2f(v) : 0.0f;
                lpart[rr] += e;
                ps[wid][di][fj * 16 + lr] = f2b(e);
            }
        __builtin_amdgcn_s_setprio(1);
#pragma unroll
        for (int kc = 0; kc < 2; kc++) {
            bf16x8 ap = *reinterpret_cast<const bf16x8*>(&ps[wid][lr][kc * 32 + lg * 8]);
#pragma unroll
            for (int nd = 0; nd < 4; nd++) {
                bf16x8 bv = *reinterpret_cast<const bf16x8*>(
                    &vsh[nd * 16 + lr][(kc * 4 + lg) ^ xs]);
                acc[nd] = __builtin_amdgcn_mfma_f32_16x16x32_bf16(ap, bv, acc[nd], 0, 0, 0);
            }
        }
        __builtin_amdgcn_s_setprio(0);

        if (more) {
            __syncthreads();  // readers of tile t done; drains vmcnt -> regs valid
            ksh[srow][sc] = kreg;
            vsh[srow][sc] = vreg;
            {
                int cw = (jrb >> 6) % 3;  // chunk freed by this tile's reads
                rsh[cw * 64 + (rrow_u & 63)][sc] = rreg;
            }
            __syncthreads();  // writes visible before tile t+1 compute
        }
    }
    float l[4];
#pragma unroll
    for (int rr = 0; rr < 4; rr++) {
        float x = lpart[rr];
        x += __shfl_xor(x, 1);
        x += __shfl_xor(x, 2);
        x += __shfl_xor(x, 4);
        x += __shfl_xor(x, 8);
        l[rr] = x;
    }
#pragma unroll
    for (int nd = 0; nd < 4; nd++)
#pragma unroll
        for (int rr = 0; rr < 4; rr++) {
            int i = it + lg * 4 + rr;
            int d = nd * 16 + lr;
            attnv[((size_t)i * 8 + b) * 1024 + n * 64 + d] = f2b(acc[nd][rr] / l[rr]);
        }
}

// ---------------- LayerNorm over last dim (1024); y input bf16 ----------------
__global__ __launch_bounds__(256) void ln_kernel(const u16* __restrict__ y,
                                                 const float* __restrict__ gamma,
                                                 const float* __restrict__ beta,
                                                 float* __restrict__ out) {
    __shared__ float rs[8];
    int row = blockIdx.x, tid = threadIdx.x;
    ushort4 u = reinterpret_cast<const ushort4*>(y + (size_t)row * 1024)[tid];
    float v0 = b2f(u.x), v1 = b2f(u.y), v2 = b2f(u.z), v3 = b2f(u.w);
    float s = v0 + v1 + v2 + v3;
    float s2 = v0 * v0 + v1 * v1 + v2 * v2 + v3 * v3;
#pragma unroll
    for (int m = 1; m < 64; m <<= 1) {
        s += __shfl_xor(s, m);
        s2 += __shfl_xor(s2, m);
    }
    if ((tid & 63) == 0) {
        rs[tid >> 6] = s;
        rs[4 + (tid >> 6)] = s2;
    }
    __syncthreads();
    s = rs[0] + rs[1] + rs[2] + rs[3];
    s2 = rs[4] + rs[5] + rs[6] + rs[7];
    float mu = s * (1.0f / 1024.0f);
    float var = s2 * (1.0f / 1024.0f) - mu * mu;
    float inv = rsqrtf(var + 1e-5f);
    float4 g = reinterpret_cast<const float4*>(gamma)[tid];
    float4 be = reinterpret_cast<const float4*>(beta)[tid];
    float4 o;
    o.x = (v0 - mu) * inv * g.x + be.x;
    o.y = (v1 - mu) * inv * g.y + be.y;
    o.z = (v2 - mu) * inv * g.z + be.z;
    o.w = (v3 - mu) * inv * g.w + be.w;
    reinterpret_cast<float4*>(out + (size_t)row * 1024)[tid] = o;
}

extern "C" void kernel_launch(void* const* d_in, const int* in_sizes, int n_in,
                              void* d_out, int out_size, void* d_ws, size_t ws_size,
                              hipStream_t stream) {
    (void)in_sizes; (void)n_in; (void)out_size; (void)ws_size;
    const float* w_in  = (const float*)d_in[0];
    const float* r_in  = (const float*)d_in[1];
    const float* mems  = (const float*)d_in[2];
    const float* bw    = (const float*)d_in[3];
    const float* brr   = (const float*)d_in[4];
    const float* Wq    = (const float*)d_in[5];
    const float* Wkv   = (const float*)d_in[6];
    const float* Wr    = (const float*)d_in[7];
    const float* br    = (const float*)d_in[8];
    const float* Wo    = (const float*)d_in[9];
    const float* bo    = (const float*)d_in[10];
    const float* gamma = (const float*)d_in[11];
    const float* beta  = (const float*)d_in[12];

    char* base = (char*)d_ws;
    size_t off = 0;
    auto alloc = [&](size_t bytes) -> char* {
        char* p = base + off;
        off += (bytes + 255) & ~(size_t)255;
        return p;
    };
    u16* cat_b = (u16*)alloc((size_t)8192 * 1024 * 2);
    u16* r_b   = (u16*)alloc((size_t)1024 * 1024 * 2);
    u16* Wq_b  = (u16*)alloc((size_t)1024 * 1024 * 2);
    u16* Wkv_b = (u16*)alloc((size_t)2048 * 1024 * 2);
    u16* Wr_b  = (u16*)alloc((size_t)1024 * 1024 * 2);
    u16* Wo_b  = (u16*)alloc((size_t)1024 * 1024 * 2);
    u16* qw_b  = (u16*)alloc((size_t)4096 * 1024 * 2);
    u16* qr_b  = (u16*)alloc((size_t)4096 * 1024 * 2);
    u16* k_b   = (u16*)alloc((size_t)128 * 1024 * 64 * 2);
    u16* vt_b  = (u16*)alloc((size_t)128 * 64 * 1024 * 2);
    u16* rk_b  = (u16*)alloc((size_t)16 * 1024 * 64 * 2);
    u16* av_b  = (u16*)alloc((size_t)4096 * 1024 * 2);
    u16* y     = (u16*)cat_b;  // alias: cat dead after GEMMs; y (bf16) written after attention

    prep_kernel<<<14336, 256, 0, stream>>>(mems, w_in, r_in, Wq, Wkv, Wr, Wo,
                                           cat_b, r_b, Wq_b, Wkv_b, Wr_b, Wo_b);

    kv_gemm<<<dim3(32, 8), 512, 0, stream>>>(cat_b, Wkv_b, k_b, vt_b);
    qr_gemm<<<320, 256, 0, stream>>>(cat_b, Wq_b, r_b, Wr_b, bw, brr, br,
                                     qw_b, qr_b, rk_b);

    attn_kernel<<<512, 512, 0, stream>>>(qw_b, qr_b, k_b, vt_b, rk_b, av_b);

    gemm_out<<<dim3(32, 8), 256, 0, stream>>>(av_b, Wo_b, w_in, bo, y);

    ln_kernel<<<4096, 256, 0, stream>>>(y, gamma, beta, (float*)d_out);
}